// Round 9
// baseline (133.175 us; speedup 1.0000x reference)
//
#include <hip/hip_runtime.h>

// Problem constants
#define T_STEPS 128
#define BATCH   64
#define DIMX    32
#define S_SUP   1024
#define NROW    8192          // T*B
#define OUT_H_SZ   (T_STEPS*BATCH*4)      // 32768
#define OUT_RBF_SZ (NROW*S_SUP)           // 8388608

#define INV2PI 0.15915494309189535f
#define L2E    1.4426950408889634f

__device__ __forceinline__ float rcp_fast(float x)  { return __builtin_amdgcn_rcpf(x); }
__device__ __forceinline__ float exp2_fast(float x) { return __builtin_amdgcn_exp2f(x); }
// raw v_cos_f32: cos(2*pi*x). All angles pre-scaled by 1/2pi upstream.
__device__ __forceinline__ float cos_rev(float x)   { return __builtin_amdgcn_cosf(x); }

// DPP lane permutes (VALU-rate cross-lane, no LDS pipe / lgkmcnt)
template<int CTRL>
__device__ __forceinline__ float dpp_perm(float v) {
    return __builtin_bit_cast(float,
        __builtin_amdgcn_mov_dpp(__builtin_bit_cast(int, v), CTRL, 0xF, 0xF, true));
}
template<int K>
__device__ __forceinline__ float quad_bcast(float v) { return dpp_perm<K * 0x55>(v); }
#define DPP_SHL8 0x108   // row_shl:8
#define DPP_SHR8 0x118   // row_shr:8

// Direction-proof XOR-8 within a 16-lane DPP row (R6-harness-proven): for
// every lane exactly one of {row_shl:8, row_shr:8} hits the partner (lane^8)
// and the other is OUT OF ROW -> bound_ctrl returns 0. Sum = partner value.
__device__ __forceinline__ float xor8(float v) {
    return dpp_perm<DPP_SHL8>(v) + dpp_perm<DPP_SHR8>(v);
}

// ---------------------------------------------------------------------------
// Kernel 1: pre[row][g][w] = (b_g[w] + p_g[w] + sum_d x[row][d]*W_g[w][d]) / 2pi
// (pre-scaled to revolutions so the LSTM feeds v_cos directly)
// ---------------------------------------------------------------------------
__global__ __launch_bounds__(256) void pre_kernel(
    const float* __restrict__ x,
    const float* __restrict__ Wf, const float* __restrict__ bf,
    const float* __restrict__ Wi, const float* __restrict__ bi,
    const float* __restrict__ Wu, const float* __restrict__ bu,
    const float* __restrict__ Wo, const float* __restrict__ bo,
    const float* __restrict__ pf, const float* __restrict__ pi,
    const float* __restrict__ pu, const float* __restrict__ po,
    float* __restrict__ pre)
{
    const int tid = threadIdx.x;
    const int rl  = tid >> 4;          // 16 rows per block
    const int gw  = tid & 15;
    const int g   = gw >> 2, w = gw & 3;
    const int row = blockIdx.x * 16 + rl;

    __shared__ float xs[16 * DIMX];
    if (tid < 128) {
        ((float4*)xs)[tid] = ((const float4*)(x + (size_t)blockIdx.x * 16 * DIMX))[tid];
    }
    __syncthreads();

    const float* W  = (g == 0) ? Wf : (g == 1) ? Wi : (g == 2) ? Wu : Wo;
    const float* bb = (g == 0) ? bf : (g == 1) ? bi : (g == 2) ? bu : bo;
    const float* pp = (g == 0) ? pf : (g == 1) ? pi : (g == 2) ? pu : po;

    float acc = bb[w] + pp[w];
    const float* Wr = W + w * 36;      // row stride D+H = 36
    const float* xr = xs + rl * DIMX;
#pragma unroll
    for (int d = 0; d < DIMX; d++) acc += xr[d] * Wr[d];

    pre[(row * 4 + g) * 4 + w] = acc * INV2PI;
}

// ---------------------------------------------------------------------------
// Kernel 2 (fused, 512 threads/block):
//   blocks 0,1 = sequential LSTM: merge of three harness-proven pieces.
//     - R8 split: 4 FULL waves/block on 2 CUs -> 1 wave/SIMD, no co-resident
//       issue interference. Model (5-for-5 over R0-R8): period = chain-sum +
//       co-resident issue; at 1 wave/SIMD only CHAIN LATENCY matters.
//     - R6 DPP lane layout (lane = b_mid*16 + wp*8 + b_lo*4 + g): ALL
//       cross-lane in DPP (quad_bcast + direction-proof xor8) -> zero LDS
//       round-trips on the recurrence. R6 regressed at 2 waves/SIMD (DPP
//       spends issue to save latency -- wrong trade there, right trade here).
//     - R7 activations: f/i/o sigmoid deg-7 odd poly (no trans), U + tanh(c)
//       exact Pade(5,4) (1 rcp each). Transpose reads sigmoid regs for F/I/O
//       and Pade regs for U -- no per-lane select.
//   blocks 2..257 = rbf+qk tiles 32 n x 1024 s, 2 s-columns per thread
// ---------------------------------------------------------------------------
__global__ __launch_bounds__(512, 2) void fused_kernel(
    const float* __restrict__ x,  const float* __restrict__ sv,
    const float* __restrict__ Wf, const float* __restrict__ bf,
    const float* __restrict__ Wi, const float* __restrict__ bi,
    const float* __restrict__ Wu, const float* __restrict__ bu,
    const float* __restrict__ Wo, const float* __restrict__ bo,
    const float* __restrict__ pf, const float* __restrict__ pi,
    const float* __restrict__ pu, const float* __restrict__ po,
    const float* __restrict__ qkp, const float* __restrict__ pre,
    float* __restrict__ out_h, float* __restrict__ out_rbf, float* __restrict__ out_qk)
{
    __shared__ float xs[32 * DIMX];   // rbf path: 32-row x tile (4 KB)
    __shared__ float xn2[32];         // pre-scaled by -log2(e)
    const int tid = threadIdx.x;

    if (blockIdx.x < 2) {
        // ====== LSTM: 4 full waves (1/SIMD), lane = b_mid*16+wp*8+b_lo*4+g ==
        if (tid >= 256) return;          // waves 4-7 idle (no barrier here)
        __builtin_amdgcn_s_setprio(3);   // win issue arbitration vs rbf waves
        const int lane = tid & 63;
        const int wv   = tid >> 6;               // wave 0..3
        const int g    = lane & 3;               // gate (quad position)
        const int wp   = (lane >> 3) & 1;        // wire pair (wires 2wp, 2wp+1)
        const int bl   = ((lane >> 4) << 1) | ((lane >> 2) & 1);  // 0..7
        const int b    = blockIdx.x * 32 + wv * 8 + bl;           // global batch
        const bool iswp = wp != 0;
        const bool selB = ((lane >> 1) & 1) != 0;  // bit1: owned-wire reg select
        const int wown  = 2 * wp + ((lane >> 1) & 1);
        const int hbase = b * 4 + wown;

        const float* W = (g == 0) ? Wf : (g == 1) ? Wi : (g == 2) ? Wu : Wo;
        const int wA = 2 * wp;
        // weight order permuted to h arrival order: {2wp, 2wp+1, 2-2wp, 3-2wp}
        const int p0 = 2 * wp, p1 = 2 * wp + 1, p2 = 2 - 2 * wp, p3 = 3 - 2 * wp;
        float WhA[4], WhB[4];
        WhA[0] = W[ wA      * 36 + 32 + p0] * INV2PI;
        WhA[1] = W[ wA      * 36 + 32 + p1] * INV2PI;
        WhA[2] = W[ wA      * 36 + 32 + p2] * INV2PI;
        WhA[3] = W[ wA      * 36 + 32 + p3] * INV2PI;
        WhB[0] = W[(wA + 1) * 36 + 32 + p0] * INV2PI;
        WhB[1] = W[(wA + 1) * 36 + 32 + p1] * INV2PI;
        WhB[2] = W[(wA + 1) * 36 + 32 + p2] * INV2PI;
        WhB[3] = W[(wA + 1) * 36 + 32 + p3] * INV2PI;

        // sigmoid odd-poly coeffs: sigma(r) = 0.5 + r*(S1 + q*(S3 + q*(S5 + q*S7)))
        // = 0.5 + 0.5*tanh(r/2) Taylor in (r/2); alternating-series err <= 2.2e-5
        const float S1 = 0.25f;
        const float S3 = -2.0833334e-2f;   // -1/48
        const float S5 =  2.0833334e-3f;   //  1/480
        const float S7 = -2.1081349e-4f;   // -17/80640

        float h = 0.f, c = 0.f;
        const float2* prep2 = (const float2*)pre;
        const int pbase = b * 8 + g * 2 + wp;   // float2 index within a t slab

        // One LSTM step on an already-loaded float2 (this lane's 2 wires).
        auto lstm_step = [&](int t, float2 cur) {
            // h for wires in arrival order: own wp-group (2wp, 2wp+1), partner's
            float hXa = quad_bcast<0>(h);   // wire 2wp   (owner: quad lane 0)
            float hXb = quad_bcast<2>(h);   // wire 2wp+1 (owner: quad lane 2)
            float hYa = xor8(hXa);          // wire 2-2wp
            float hYb = xor8(hXb);          // wire 3-2wp

            // angles (revolutions), matvec as 2 parallel pairs (chain 3 stages)
            float eA = fmaf(hXb, WhA[1], fmaf(hXa, WhA[0], cur.x));
            float fA = fmaf(hYb, WhA[3], hYa * WhA[2]);
            float aA = eA + fA;
            float eB = fmaf(hXb, WhB[1], fmaf(hXa, WhB[0], cur.y));
            float fB = fmaf(hYb, WhB[3], hYa * WhB[2]);
            float aB = eB + fB;
            float CA = cos_rev(aA), CB = cos_rev(aB);

            // partner pair's cosines (same gate, other wp) via XOR8
            float DA = xor8(CA);
            float DB = xor8(CB);

            // r for this lane's 2 wires:
            //  wp0: CA=C0 CB=C1 DA=C2 DB=C3: rA=r0=C1*C2*C3, rB=r1=C0*C1
            //  wp1: CA=C2 CB=C3 DA=C0 DB=C1: rA=r2=C0*C1*C2, rB=r3=rA*C3
            float P  = DA * DB;
            float t1 = iswp ? CA : CB;
            float rA = t1 * P;
            float t2 = iswp ? rA : CA;
            float rB = t2 * CB;

            float qA = rA * rA, qB = rB * rB;
            // sigmoid poly (consumed by F/I/O gathers) -- no trans ops
            float pA  = fmaf(qA, fmaf(qA, fmaf(qA, S7, S5), S3), S1);
            float pB  = fmaf(qB, fmaf(qB, fmaf(qB, S7, S5), S3), S1);
            float sgA = fmaf(rA, pA, 0.5f);
            float sgB = fmaf(rB, pB, 0.5f);
            // tanh Pade(5,4) (consumed by the U gather) -- 1 rcp
            float nA  = rA * fmaf(qA, qA + 105.f, 945.f);
            float dA  = fmaf(qA, fmaf(qA, 15.f, 420.f), 945.f);
            float thA = nA * rcp_fast(dA);
            float nB  = rB * fmaf(qB, qB + 105.f, 945.f);
            float dB  = fmaf(qB, fmaf(qB, 15.f, 420.f), 945.f);
            float thB = nB * rcp_fast(dB);

            // gate-transpose: quad_bcast from gate-lane K; F/I/O read the
            // sigmoid regs, U reads the Pade regs; pick A/B reg by bit1
            float Fa = quad_bcast<0>(sgA), Fb = quad_bcast<0>(sgB);
            float Ia = quad_bcast<1>(sgA), Ib = quad_bcast<1>(sgB);
            float Ua = quad_bcast<2>(thA), Ub = quad_bcast<2>(thB);
            float Oa = quad_bcast<3>(sgA), Ob = quad_bcast<3>(sgB);
            float F = selB ? Fb : Fa;
            float I = selB ? Ib : Ia;
            float U = selB ? Ub : Ua;
            float O = selB ? Ob : Oa;

            // state update; tanh(c) via Pade(5,4), |c| <= 2.07 provably
            c = fmaf(F, c, I * U);
            float qc = c * c;
            float nc = c * fmaf(qc, qc + 105.f, 945.f);
            float dc = fmaf(qc, fmaf(qc, 15.f, 420.f), 945.f);
            h = O * (nc * rcp_fast(dc));

            // dup lanes (bit0 pair) store same value to same address (harmless)
            out_h[t * 256 + hbase] = h;
        };

        // Chunked double-buffer: 8 cur + 8 nxt float2 regs; loads issued a
        // full chunk ahead. float2 index for step t is t*512 + pbase.
        float2 cb0, cb1, cb2, cb3, cb4, cb5, cb6, cb7;
        cb0 = prep2[pbase];            cb1 = prep2[pbase + 512];
        cb2 = prep2[pbase + 1024];     cb3 = prep2[pbase + 1536];
        cb4 = prep2[pbase + 2048];     cb5 = prep2[pbase + 2560];
        cb6 = prep2[pbase + 3072];     cb7 = prep2[pbase + 3584];

#pragma unroll 1
        for (int tt = 0; tt < T_STEPS; tt += 8) {
            // issue next-chunk loads (branch-free clamped base)
            int nb = tt + 8; nb = (nb > T_STEPS - 8) ? (T_STEPS - 8) : nb;
            const float2* pc = prep2 + pbase + nb * 512;
            float2 nb0 = pc[0];
            float2 nb1 = pc[512];
            float2 nb2 = pc[1024];
            float2 nb3 = pc[1536];
            float2 nb4 = pc[2048];
            float2 nb5 = pc[2560];
            float2 nb6 = pc[3072];
            float2 nb7 = pc[3584];
            __builtin_amdgcn_sched_barrier(0);  // pin loads ahead of compute

            lstm_step(tt + 0, cb0);
            lstm_step(tt + 1, cb1);
            lstm_step(tt + 2, cb2);
            lstm_step(tt + 3, cb3);
            lstm_step(tt + 4, cb4);
            lstm_step(tt + 5, cb5);
            lstm_step(tt + 6, cb6);
            lstm_step(tt + 7, cb7);

            cb0 = nb0; cb1 = nb1; cb2 = nb2; cb3 = nb3;
            cb4 = nb4; cb5 = nb5; cb6 = nb6; cb7 = nb7;
        }
    } else {
        // ================= rbf + qk tile: 32 n x 1024 s, 2 s per thread ======
        const int bid = blockIdx.x - 2;
        const int n0  = bid * 32;

        float4* xs4 = (float4*)xs;
        const float4* xg = (const float4*)(x + (size_t)n0 * DIMX);
        if (tid < 256) {
            float4 t0v = xg[tid];
            xs4[tid] = t0v;
            // per-row |x|^2: 8 lanes per row, xor-reduce; store -log2e*|x|^2
            float p0 = t0v.x * t0v.x + t0v.y * t0v.y + t0v.z * t0v.z + t0v.w * t0v.w;
            p0 += __shfl_xor(p0, 1);
            p0 += __shfl_xor(p0, 2);
            p0 += __shfl_xor(p0, 4);
            if ((tid & 7) == 0) xn2[tid >> 3] = -L2E * p0;
        }

        // this thread's two support vectors (s and s+512)
        const int sA = tid, sB = tid + 512;
        float4 svv[8], svw[8];
        const float4* svgA = (const float4*)(sv + (size_t)sA * DIMX);
        const float4* svgB = (const float4*)(sv + (size_t)sB * DIMX);
#pragma unroll
        for (int k = 0; k < 8; k++) { svv[k] = svgA[k]; svw[k] = svgB[k]; }
        float sn2A = 0.f, sn2B = 0.f;
#pragma unroll
        for (int k = 0; k < 8; k++) {
            sn2A += svv[k].x * svv[k].x + svv[k].y * svv[k].y + svv[k].z * svv[k].z + svv[k].w * svv[k].w;
            sn2B += svw[k].x * svw[k].x + svw[k].y * svw[k].y + svw[k].z * svw[k].z + svw[k].w * svw[k].w;
        }
        const float snlA = -L2E * sn2A;
        const float snlB = -L2E * sn2B;

        // qk s-side: B_w = sv_w/2 + qk_w, pre-scaled to revolutions
        const float q0 = qkp[0], q1 = qkp[1], q2 = qkp[2], q3 = qkp[3];
        const float C05 = 0.5f * INV2PI;
        const float BA0 = fmaf(0.5f, svv[0].x, q0) * INV2PI;
        const float BA1 = fmaf(0.5f, svv[0].y, q1) * INV2PI;
        const float BA2 = fmaf(0.5f, svv[0].z, q2) * INV2PI;
        const float BA3 = fmaf(0.5f, svv[0].w, q3) * INV2PI;
        const float BB0 = fmaf(0.5f, svw[0].x, q0) * INV2PI;
        const float BB1 = fmaf(0.5f, svw[0].y, q1) * INV2PI;
        const float BB2 = fmaf(0.5f, svw[0].z, q2) * INV2PI;
        const float BB3 = fmaf(0.5f, svw[0].w, q3) * INV2PI;
        __syncthreads();

#pragma unroll 2
        for (int n = 0; n < 32; n++) {
            const float4* xr4 = (const float4*)(xs + n * DIMX);   // broadcast reads
            float4 xv0 = xr4[0];
            float dotA = xv0.x * svv[0].x + xv0.y * svv[0].y + xv0.z * svv[0].z + xv0.w * svv[0].w;
            float dotB = xv0.x * svw[0].x + xv0.y * svw[0].y + xv0.z * svw[0].z + xv0.w * svw[0].w;
#pragma unroll
            for (int k = 1; k < 8; k++) {
                float4 xv = xr4[k];
                dotA += xv.x * svv[k].x + xv.y * svv[k].y + xv.z * svv[k].z + xv.w * svv[k].w;
                dotB += xv.x * svw[k].x + xv.y * svw[k].y + xv.z * svw[k].z + xv.w * svw[k].w;
            }
            // rbf: exp(-(|x|^2+|s|^2-2dot)) = exp2(2*L2E*dot - L2E|x|^2 - L2E|s|^2)
            float xnl = xn2[n];
            float rbA = exp2_fast(fmaf(2.f * L2E, dotA, xnl + snlA));
            float rbB = exp2_fast(fmaf(2.f * L2E, dotB, xnl + snlB));

            float qvA = cos_rev(fmaf(C05, xv0.x, BA0)) * cos_rev(fmaf(C05, xv0.y, BA1))
                      * cos_rev(fmaf(C05, xv0.z, BA2)) * cos_rev(fmaf(C05, xv0.w, BA3));
            float qvB = cos_rev(fmaf(C05, xv0.x, BB0)) * cos_rev(fmaf(C05, xv0.y, BB1))
                      * cos_rev(fmaf(C05, xv0.z, BB2)) * cos_rev(fmaf(C05, xv0.w, BB3));
            qvA = fabsf(qvA);
            qvB = fabsf(qvB);

            const size_t rowb = (size_t)(n0 + n) * S_SUP;
            out_rbf[rowb + sA] = rbA;
            out_rbf[rowb + sB] = rbB;
            out_qk [rowb + sA] = qvA;
            out_qk [rowb + sB] = qvB;
        }
    }
}

// ---------------------------------------------------------------------------
extern "C" void kernel_launch(void* const* d_in, const int* in_sizes, int n_in,
                              void* d_out, int out_size, void* d_ws, size_t ws_size,
                              hipStream_t stream)
{
    const float* x   = (const float*)d_in[0];
    const float* sv  = (const float*)d_in[1];
    const float* Wf  = (const float*)d_in[2];
    const float* bf  = (const float*)d_in[3];
    const float* Wi  = (const float*)d_in[4];
    const float* bi  = (const float*)d_in[5];
    const float* Wu  = (const float*)d_in[6];
    const float* bu  = (const float*)d_in[7];
    const float* Wo  = (const float*)d_in[8];
    const float* bo  = (const float*)d_in[9];
    const float* pf  = (const float*)d_in[10];
    const float* pi  = (const float*)d_in[11];
    const float* pu  = (const float*)d_in[12];
    const float* po  = (const float*)d_in[13];
    const float* qkp = (const float*)d_in[14];

    float* out     = (float*)d_out;
    float* out_h   = out;
    float* out_rbf = out + OUT_H_SZ;
    float* out_qk  = out + OUT_H_SZ + OUT_RBF_SZ;

    float* pre = (float*)d_ws;   // 512 KB scratch (NROW*16 floats, in revolutions)

    pre_kernel<<<NROW / 16, 256, 0, stream>>>(x, Wf, bf, Wi, bi, Wu, bu, Wo, bo,
                                              pf, pi, pu, po, pre);
    fused_kernel<<<2 + 256, 512, 0, stream>>>(
        x, sv, Wf, bf, Wi, bi, Wu, bu, Wo, bo, pf, pi, pu, po, qkp, pre,
        out_h, out_rbf, out_qk);
}

// Round 10
// 129.231 us; speedup vs baseline: 1.0305x; 1.0305x over previous
//
#include <hip/hip_runtime.h>

// Problem constants
#define T_STEPS 128
#define BATCH   64
#define DIMX    32
#define S_SUP   1024
#define NROW    8192          // T*B
#define OUT_H_SZ   (T_STEPS*BATCH*4)      // 32768
#define OUT_RBF_SZ (NROW*S_SUP)           // 8388608

#define INV2PI 0.15915494309189535f
#define L2E    1.4426950408889634f

__device__ __forceinline__ float rcp_fast(float x)  { return __builtin_amdgcn_rcpf(x); }
__device__ __forceinline__ float exp2_fast(float x) { return __builtin_amdgcn_exp2f(x); }
// raw v_cos_f32: cos(2*pi*x). All angles pre-scaled by 1/2pi upstream.
__device__ __forceinline__ float cos_rev(float x)   { return __builtin_amdgcn_cosf(x); }

// DPP lane permutes within each quad (VALU-rate cross-lane)
template<int CTRL>
__device__ __forceinline__ float dpp_perm(float v) {
    return __builtin_bit_cast(float,
        __builtin_amdgcn_mov_dpp(__builtin_bit_cast(int, v), CTRL, 0xF, 0xF, true));
}
#define DPP_XOR1 0xB1   // quad_perm [1,0,3,2]

// ds_swizzle BitMode: src_lane = ((lane & and) | or) ^ xor, offset = xor<<10|or<<5|and
template<int OFF>
__device__ __forceinline__ float swz(float v) {
    return __builtin_bit_cast(float,
        __builtin_amdgcn_ds_swizzle(__builtin_bit_cast(int, v), OFF));
}

// ---------------------------------------------------------------------------
// Kernel 1: pre[row][g][w] = (b_g[w] + p_g[w] + sum_d x[row][d]*W_g[w][d]) / 2pi
// (pre-scaled to revolutions so the LSTM feeds v_cos directly)
// ---------------------------------------------------------------------------
__global__ __launch_bounds__(256) void pre_kernel(
    const float* __restrict__ x,
    const float* __restrict__ Wf, const float* __restrict__ bf,
    const float* __restrict__ Wi, const float* __restrict__ bi,
    const float* __restrict__ Wu, const float* __restrict__ bu,
    const float* __restrict__ Wo, const float* __restrict__ bo,
    const float* __restrict__ pf, const float* __restrict__ pi,
    const float* __restrict__ pu, const float* __restrict__ po,
    float* __restrict__ pre)
{
    const int tid = threadIdx.x;
    const int rl  = tid >> 4;          // 16 rows per block
    const int gw  = tid & 15;
    const int g   = gw >> 2, w = gw & 3;
    const int row = blockIdx.x * 16 + rl;

    __shared__ float xs[16 * DIMX];
    if (tid < 128) {
        ((float4*)xs)[tid] = ((const float4*)(x + (size_t)blockIdx.x * 16 * DIMX))[tid];
    }
    __syncthreads();

    const float* W  = (g == 0) ? Wf : (g == 1) ? Wi : (g == 2) ? Wu : Wo;
    const float* bb = (g == 0) ? bf : (g == 1) ? bi : (g == 2) ? bu : bo;
    const float* pp = (g == 0) ? pf : (g == 1) ? pi : (g == 2) ? pu : po;

    float acc = bb[w] + pp[w];
    const float* Wr = W + w * 36;      // row stride D+H = 36
    const float* xr = xs + rl * DIMX;
#pragma unroll
    for (int d = 0; d < DIMX; d++) acc += xr[d] * Wr[d];

    pre[(row * 4 + g) * 4 + w] = acc * INV2PI;
}

// ---------------------------------------------------------------------------
// Kernel 2 (fused, 512 threads/block):
//   blocks 0,1 = sequential LSTM split across 2 CUs: 4 FULL waves each
//     (1 wave/SIMD), 32 batches each. BEST-MEASURED config (R8, 129.7 us).
//     Measured cost model (R0-R9, 6 experiments): a lone in-order wave pays
//     ~6-8 cy/VALU op and ~20-25 cy/trans REGARDLESS of dependence; with
//     co-resident waves, add their issue time. Hence: 1 wave/SIMD (R8 beat
//     R4's 2/SIMD), ds_swizzle over DPP-xor8 (fewer ops: R9 regressed),
//     poly/Pade acts are op-neutral vs exp2 (R7 null) but keep the proven
//     numerics. Per-step ~65 ops ~= 640 cy -> ~34 us LSTM floor.
//   blocks 2..257 = rbf+qk tiles 32 n x 1024 s, 2 s-columns per thread
// ---------------------------------------------------------------------------
__global__ __launch_bounds__(512, 2) void fused_kernel(
    const float* __restrict__ x,  const float* __restrict__ sv,
    const float* __restrict__ Wf, const float* __restrict__ bf,
    const float* __restrict__ Wi, const float* __restrict__ bi,
    const float* __restrict__ Wu, const float* __restrict__ bu,
    const float* __restrict__ Wo, const float* __restrict__ bo,
    const float* __restrict__ pf, const float* __restrict__ pi,
    const float* __restrict__ pu, const float* __restrict__ po,
    const float* __restrict__ qkp, const float* __restrict__ pre,
    float* __restrict__ out_h, float* __restrict__ out_rbf, float* __restrict__ out_qk)
{
    __shared__ float xs[32 * DIMX];   // rbf path: 32-row x tile (4 KB)
    __shared__ float xn2[32];         // pre-scaled by -log2(e)
    const int tid = threadIdx.x;

    if (blockIdx.x < 2) {
        // ============ LSTM: 4 full waves, unit = (b, g, wp), 32 batches =====
        if (tid >= 256) return;          // waves 4-7 idle (no barrier here)
        __builtin_amdgcn_s_setprio(3);   // win issue arbitration vs rbf waves
        const int lane = tid & 63;
        const int wv   = tid >> 6;             // wave 0..3
        const int g    = (lane >> 1) & 3;      // gate
        const int wp   = lane & 1;             // wire pair (wires 2wp, 2wp+1)
        const bool iswp = wp != 0;
        const bool hi2  = (lane & 4) != 0;     // reg-select for transpose
        const int b     = blockIdx.x * 32 + wv * 8 + (lane >> 3);   // global batch
        const int wown  = 2 * wp + ((lane >> 2) & 1);   // owned wire (dup x2)
        const int hbase = b * 4 + wown;

        const float* W = (g == 0) ? Wf : (g == 1) ? Wi : (g == 2) ? Wu : Wo;
        float WhA[4], WhB[4];            // hidden rows for wires 2wp, 2wp+1
        const int wA = 2 * wp;
#pragma unroll
        for (int j = 0; j < 4; j++) {
            WhA[j] = W[ wA      * 36 + 32 + j] * INV2PI;
            WhB[j] = W[(wA + 1) * 36 + 32 + j] * INV2PI;
        }

        // sigmoid odd-poly coeffs: sigma(r) = 0.5 + r*(S1 + q*(S3 + q*(S5 + q*S7)))
        // = 0.5 + 0.5*tanh(r/2) Taylor in (r/2); alternating-series err <= 2.2e-5
        const float S1 = 0.25f;
        const float S3 = -2.0833334e-2f;   // -1/48
        const float S5 =  2.0833334e-3f;   //  1/480
        const float S7 = -2.1081349e-4f;   // -17/80640

        float h = 0.f, c = 0.f;
        const float2* prep2 = (const float2*)pre;
        const int pbase = b * 8 + g * 2 + wp;   // float2 index within a t slab

        // One LSTM step on an already-loaded float2 (this lane's 2 wires).
        auto lstm_step = [&](int t, float2 cur) {
            // gather h0..h3 from owner lanes e={0,4,1,5} (wires 0,1,2,3)
            float h0 = swz<0x018>(h);
            float h1 = swz<0x098>(h);
            float h2 = swz<0x038>(h);
            float h3 = swz<0x0B8>(h);

            // angles (revolutions), matvec as 2 parallel pairs (chain 3 stages)
            float eA = fmaf(h1, WhA[1], fmaf(h0, WhA[0], cur.x));
            float fA = fmaf(h3, WhA[3], h2 * WhA[2]);
            float aA = eA + fA;
            float eB = fmaf(h1, WhB[1], fmaf(h0, WhB[0], cur.y));
            float fB = fmaf(h3, WhB[3], h2 * WhB[2]);
            float aB = eB + fB;
            float CA = cos_rev(aA), CB = cos_rev(aB);

            // partner pair's cosines (same gate, other wp) via quad DPP xor1
            float DA = dpp_perm<DPP_XOR1>(CA);
            float DB = dpp_perm<DPP_XOR1>(CB);

            // r for this lane's 2 wires:
            //  wp0: rA=r0=C1*C2*C3, rB=r1=C0*C1 ; wp1: rA=r2=C0*C1*C2, rB=r3=rA*C3
            float P  = DA * DB;
            float t1 = iswp ? CA : CB;
            float rA = t1 * P;
            float t2 = iswp ? rA : CA;
            float rB = t2 * CB;

            float qA = rA * rA, qB = rB * rB;
            // sigmoid poly (consumed by F/I/O gathers) -- no trans ops
            float pA  = fmaf(qA, fmaf(qA, fmaf(qA, S7, S5), S3), S1);
            float pB  = fmaf(qB, fmaf(qB, fmaf(qB, S7, S5), S3), S1);
            float sgA = fmaf(rA, pA, 0.5f);
            float sgB = fmaf(rB, pB, 0.5f);
            // tanh Pade(5,4) (consumed by the U gather) -- 1 rcp
            float nA  = rA * fmaf(qA, qA + 105.f, 945.f);
            float dA  = fmaf(qA, fmaf(qA, 15.f, 420.f), 945.f);
            float thA = nA * rcp_fast(dA);
            float nB  = rB * fmaf(qB, qB + 105.f, 945.f);
            float dB  = fmaf(qB, fmaf(qB, 15.f, 420.f), 945.f);
            float thB = nB * rcp_fast(dB);

            // gate-transpose: src lane = (lane & 0b11001) | (gate<<1);
            // F/I/O read the sigmoid regs, U reads the pade regs (no select)
            float FA = swz<0x019>(sgA), FB = swz<0x019>(sgB);
            float IA = swz<0x059>(sgA), IB = swz<0x059>(sgB);
            float UA = swz<0x099>(thA), UB = swz<0x099>(thB);
            float OA = swz<0x0D9>(sgA), OB = swz<0x0D9>(sgB);
            float F = hi2 ? FB : FA;
            float I = hi2 ? IB : IA;
            float U = hi2 ? UB : UA;
            float O = hi2 ? OB : OA;

            // state update; tanh(c) via Pade(5,4), |c| <= 2.07 provably
            c = fmaf(F, c, I * U);
            float qc = c * c;
            float nc = c * fmaf(qc, qc + 105.f, 945.f);
            float dc = fmaf(qc, fmaf(qc, 15.f, 420.f), 945.f);
            h = O * (nc * rcp_fast(dc));

            // dup lanes store the same value to the same address (harmless)
            out_h[t * 256 + hbase] = h;
        };

        // Chunked double-buffer: 8 cur + 8 nxt float2 regs; loads issued a
        // full chunk ahead. float2 index for step t is t*512 + pbase.
        float2 cb0, cb1, cb2, cb3, cb4, cb5, cb6, cb7;
        cb0 = prep2[pbase];            cb1 = prep2[pbase + 512];
        cb2 = prep2[pbase + 1024];     cb3 = prep2[pbase + 1536];
        cb4 = prep2[pbase + 2048];     cb5 = prep2[pbase + 2560];
        cb6 = prep2[pbase + 3072];     cb7 = prep2[pbase + 3584];

#pragma unroll 1
        for (int tt = 0; tt < T_STEPS; tt += 8) {
            // issue next-chunk loads (branch-free clamped base)
            int nb = tt + 8; nb = (nb > T_STEPS - 8) ? (T_STEPS - 8) : nb;
            const float2* pc = prep2 + pbase + nb * 512;
            float2 nb0 = pc[0];
            float2 nb1 = pc[512];
            float2 nb2 = pc[1024];
            float2 nb3 = pc[1536];
            float2 nb4 = pc[2048];
            float2 nb5 = pc[2560];
            float2 nb6 = pc[3072];
            float2 nb7 = pc[3584];
            __builtin_amdgcn_sched_barrier(0);  // pin loads ahead of compute

            lstm_step(tt + 0, cb0);
            lstm_step(tt + 1, cb1);
            lstm_step(tt + 2, cb2);
            lstm_step(tt + 3, cb3);
            lstm_step(tt + 4, cb4);
            lstm_step(tt + 5, cb5);
            lstm_step(tt + 6, cb6);
            lstm_step(tt + 7, cb7);

            cb0 = nb0; cb1 = nb1; cb2 = nb2; cb3 = nb3;
            cb4 = nb4; cb5 = nb5; cb6 = nb6; cb7 = nb7;
        }
    } else {
        // ================= rbf + qk tile: 32 n x 1024 s, 2 s per thread ======
        const int bid = blockIdx.x - 2;
        const int n0  = bid * 32;

        float4* xs4 = (float4*)xs;
        const float4* xg = (const float4*)(x + (size_t)n0 * DIMX);
        if (tid < 256) {
            float4 t0v = xg[tid];
            xs4[tid] = t0v;
            // per-row |x|^2: 8 lanes per row, xor-reduce; store -log2e*|x|^2
            float p0 = t0v.x * t0v.x + t0v.y * t0v.y + t0v.z * t0v.z + t0v.w * t0v.w;
            p0 += __shfl_xor(p0, 1);
            p0 += __shfl_xor(p0, 2);
            p0 += __shfl_xor(p0, 4);
            if ((tid & 7) == 0) xn2[tid >> 3] = -L2E * p0;
        }

        // this thread's two support vectors (s and s+512)
        const int sA = tid, sB = tid + 512;
        float4 svv[8], svw[8];
        const float4* svgA = (const float4*)(sv + (size_t)sA * DIMX);
        const float4* svgB = (const float4*)(sv + (size_t)sB * DIMX);
#pragma unroll
        for (int k = 0; k < 8; k++) { svv[k] = svgA[k]; svw[k] = svgB[k]; }
        float sn2A = 0.f, sn2B = 0.f;
#pragma unroll
        for (int k = 0; k < 8; k++) {
            sn2A += svv[k].x * svv[k].x + svv[k].y * svv[k].y + svv[k].z * svv[k].z + svv[k].w * svv[k].w;
            sn2B += svw[k].x * svw[k].x + svw[k].y * svw[k].y + svw[k].z * svw[k].z + svw[k].w * svw[k].w;
        }
        const float snlA = -L2E * sn2A;
        const float snlB = -L2E * sn2B;

        // qk s-side: B_w = sv_w/2 + qk_w, pre-scaled to revolutions
        const float q0 = qkp[0], q1 = qkp[1], q2 = qkp[2], q3 = qkp[3];
        const float C05 = 0.5f * INV2PI;
        const float BA0 = fmaf(0.5f, svv[0].x, q0) * INV2PI;
        const float BA1 = fmaf(0.5f, svv[0].y, q1) * INV2PI;
        const float BA2 = fmaf(0.5f, svv[0].z, q2) * INV2PI;
        const float BA3 = fmaf(0.5f, svv[0].w, q3) * INV2PI;
        const float BB0 = fmaf(0.5f, svw[0].x, q0) * INV2PI;
        const float BB1 = fmaf(0.5f, svw[0].y, q1) * INV2PI;
        const float BB2 = fmaf(0.5f, svw[0].z, q2) * INV2PI;
        const float BB3 = fmaf(0.5f, svw[0].w, q3) * INV2PI;
        __syncthreads();

#pragma unroll 2
        for (int n = 0; n < 32; n++) {
            const float4* xr4 = (const float4*)(xs + n * DIMX);   // broadcast reads
            float4 xv0 = xr4[0];
            float dotA = xv0.x * svv[0].x + xv0.y * svv[0].y + xv0.z * svv[0].z + xv0.w * svv[0].w;
            float dotB = xv0.x * svw[0].x + xv0.y * svw[0].y + xv0.z * svw[0].z + xv0.w * svw[0].w;
#pragma unroll
            for (int k = 1; k < 8; k++) {
                float4 xv = xr4[k];
                dotA += xv.x * svv[k].x + xv.y * svv[k].y + xv.z * svv[k].z + xv.w * svv[k].w;
                dotB += xv.x * svw[k].x + xv.y * svw[k].y + xv.z * svw[k].z + xv.w * svw[k].w;
            }
            // rbf: exp(-(|x|^2+|s|^2-2dot)) = exp2(2*L2E*dot - L2E|x|^2 - L2E|s|^2)
            float xnl = xn2[n];
            float rbA = exp2_fast(fmaf(2.f * L2E, dotA, xnl + snlA));
            float rbB = exp2_fast(fmaf(2.f * L2E, dotB, xnl + snlB));

            float qvA = cos_rev(fmaf(C05, xv0.x, BA0)) * cos_rev(fmaf(C05, xv0.y, BA1))
                      * cos_rev(fmaf(C05, xv0.z, BA2)) * cos_rev(fmaf(C05, xv0.w, BA3));
            float qvB = cos_rev(fmaf(C05, xv0.x, BB0)) * cos_rev(fmaf(C05, xv0.y, BB1))
                      * cos_rev(fmaf(C05, xv0.z, BB2)) * cos_rev(fmaf(C05, xv0.w, BB3));
            qvA = fabsf(qvA);
            qvB = fabsf(qvB);

            const size_t rowb = (size_t)(n0 + n) * S_SUP;
            out_rbf[rowb + sA] = rbA;
            out_rbf[rowb + sB] = rbB;
            out_qk [rowb + sA] = qvA;
            out_qk [rowb + sB] = qvB;
        }
    }
}

// ---------------------------------------------------------------------------
extern "C" void kernel_launch(void* const* d_in, const int* in_sizes, int n_in,
                              void* d_out, int out_size, void* d_ws, size_t ws_size,
                              hipStream_t stream)
{
    const float* x   = (const float*)d_in[0];
    const float* sv  = (const float*)d_in[1];
    const float* Wf  = (const float*)d_in[2];
    const float* bf  = (const float*)d_in[3];
    const float* Wi  = (const float*)d_in[4];
    const float* bi  = (const float*)d_in[5];
    const float* Wu  = (const float*)d_in[6];
    const float* bu  = (const float*)d_in[7];
    const float* Wo  = (const float*)d_in[8];
    const float* bo  = (const float*)d_in[9];
    const float* pf  = (const float*)d_in[10];
    const float* pi  = (const float*)d_in[11];
    const float* pu  = (const float*)d_in[12];
    const float* po  = (const float*)d_in[13];
    const float* qkp = (const float*)d_in[14];

    float* out     = (float*)d_out;
    float* out_h   = out;
    float* out_rbf = out + OUT_H_SZ;
    float* out_qk  = out + OUT_H_SZ + OUT_RBF_SZ;

    float* pre = (float*)d_ws;   // 512 KB scratch (NROW*16 floats, in revolutions)

    pre_kernel<<<NROW / 16, 256, 0, stream>>>(x, Wf, bf, Wi, bi, Wu, bu, Wo, bo,
                                              pf, pi, pu, po, pre);
    fused_kernel<<<2 + 256, 512, 0, stream>>>(
        x, sv, Wf, bf, Wi, bi, Wu, bu, Wo, bo, pf, pi, pu, po, qkp, pre,
        out_h, out_rbf, out_qk);
}